// Round 2
// baseline (324.739 us; speedup 1.0000x reference)
//
#include <hip/hip_runtime.h>

// Problem constants (B, LQ, LK, D from the reference)
#define B_  8
#define LQ_ 2048
#define LK_ 2048
#define D_  1024

typedef unsigned short u16;
using short8  = __attribute__((ext_vector_type(8))) short;   // 8 bf16 = 4 VGPRs (MFMA A/B frag)
using floatx4 = __attribute__((ext_vector_type(4))) float;   // MFMA C/D frag

#define GAS __attribute__((address_space(1)))
#define LAS __attribute__((address_space(3)))

__device__ __forceinline__ u16 f2bf(float f) {
  unsigned u = __float_as_uint(f);
  u += 0x7fffu + ((u >> 16) & 1u);   // round-to-nearest-even
  return (u16)(u >> 16);
}
__device__ __forceinline__ float bf2f(u16 h) {
  return __uint_as_float(((unsigned)h) << 16);
}

// ---------------------------------------------------------------------------
// prep (unchanged): blockIdx.y < 16  -> memory path: mb = bf16(memory),
//                                      mbT = bf16(memory)^T
//                   blockIdx.y >= 16 -> input path: qb = bf16(input*dot_scale)
// One designated block additionally zeroes the softmax-denominator buffer.
// ---------------------------------------------------------------------------
__global__ void prep(const float* __restrict__ in, const float* __restrict__ mem,
                     const float* __restrict__ ds, u16* __restrict__ qb,
                     u16* __restrict__ mb, u16* __restrict__ mbT,
                     float* __restrict__ denom) {
  __shared__ u16 tile[64][68];   // pad 68 to break power-of-2 bank stride
  int tid = threadIdx.x;
  int tx = tid & 15, ty = tid >> 4;
  int b = blockIdx.z;

  if (denom && blockIdx.y == 16 && blockIdx.x == 0 && blockIdx.z == 0) {
    float4 z = {0.f, 0.f, 0.f, 0.f};
    float4* d4 = (float4*)denom;
#pragma unroll
    for (int i = 0; i < (B_ * LQ_ / 4) / 256; i++)
      d4[tid + i * 256] = z;
  }

  if (blockIdx.y < 16) {
    // ---- memory path: convert + transpose ----
    int k0 = blockIdx.x * 64, d0 = blockIdx.y * 64;
    const float* mB = mem + (size_t)b * LK_ * D_;
    u16* mbB = mb  + (size_t)b * LK_ * D_;
    u16* mtB = mbT + (size_t)b * D_ * LK_;
#pragma unroll
    for (int i = 0; i < 4; i++) {
      int r = ty + 16 * i;                   // k-row within tile
      float4 v = *(const float4*)(mB + (size_t)(k0 + r) * D_ + d0 + tx * 4);
      ushort4 h;
      h.x = f2bf(v.x); h.y = f2bf(v.y); h.z = f2bf(v.z); h.w = f2bf(v.w);
      *(ushort4*)(mbB + (size_t)(k0 + r) * D_ + d0 + tx * 4) = h;
      *(ushort4*)(&tile[r][tx * 4]) = h;
    }
    __syncthreads();
#pragma unroll
    for (int i = 0; i < 4; i++) {
      int rr = ty + 16 * i;                  // d-row within tile
      ushort4 o;
      o.x = tile[tx * 4 + 0][rr];
      o.y = tile[tx * 4 + 1][rr];
      o.z = tile[tx * 4 + 2][rr];
      o.w = tile[tx * 4 + 3][rr];
      *(ushort4*)(mtB + (size_t)(d0 + rr) * LK_ + k0 + tx * 4) = o;
    }
  } else {
    // ---- input path: scale by dot_scale, convert ----
    int q0 = blockIdx.x * 64, d0 = (blockIdx.y - 16) * 64;
    const float* iB = in + (size_t)b * LQ_ * D_;
    u16* qB = qb + (size_t)b * LQ_ * D_;
    float4 s4 = *(const float4*)(ds + d0 + tx * 4);
#pragma unroll
    for (int i = 0; i < 4; i++) {
      int r = ty + 16 * i;
      float4 v = *(const float4*)(iB + (size_t)(q0 + r) * D_ + d0 + tx * 4);
      ushort4 h;
      h.x = f2bf(v.x * s4.x); h.y = f2bf(v.y * s4.y);
      h.z = f2bf(v.z * s4.z); h.w = f2bf(v.w * s4.w);
      *(ushort4*)(qB + (size_t)(q0 + r) * D_ + d0 + tx * 4) = h;
    }
  }
}

// ---------------------------------------------------------------------------
// gemm_bt: C[M,N] = A[M,K] * B[N,K]^T per batch.
// Geometry (unchanged from round 1, proven 0-bank-conflict):
//   256x256 tile, BK=64, 8 waves (2M x 4N), wave output 128x64
//   (acc[8][4] 16x16x32 frags). LDS 128 KiB = per matrix 4 planes of 16 KiB
//   [buf][khalf][256 rows][32 k], XOR chunk swizzle slot^=((row>>1)&3)
//   applied to BOTH the global_load_lds SOURCE and the ds_read address
//   (dest linear — rule 21).
// NEW SCHEDULE (m201 per-phase double-barrier, the m196-isolated lever):
//   4 phases per K-tile, phase = (MH, KK):
//     { ds_read af x4 (+bf x4 if MH==0); stage 1 half-tile;
//       s_barrier; lgkmcnt(0)+sched_barrier; setprio(1); 16 MFMA; setprio(0);
//       [counted vmcnt before closing barrier at p1/p3]; s_barrier }
//   The double barrier gives each wave one phase of desync slack: a wave
//   done with its MFMA cluster issues next-phase ds_reads while others
//   (setprio-boosted) still occupy the MFMA pipe -> LDS/MFMA pipe overlap.
//   vmcnt discipline (per-wave counts, each stage = 2 insts/thread):
//     prologue: stage tile0's 4 halves (8 insts) -> vmcnt(4)+barrier
//               guarantees k0 pair resident, k1 pair still in flight.
//     tile t p0: stage A-k0(t+1); p1: stage B-k0(t+1);
//               vmcnt(4) before p1's closing barrier -> completes k1(t) pair
//               (outstanding 8 -> 4).
//     p2: stage A-k1(t+1); p3: stage B-k1(t+1);
//               vmcnt(4) before p3's closing barrier -> completes k0(t+1)
//               pair (outstanding 8 -> 4). Never drains to 0 mid-loop.
//     last tile: no stages; p1 wait must be vmcnt(0) (outstanding == 4 ==
//               exactly the needed k1 pair; vmcnt(4) would be a no-op).
//   Residency guarantee = per-wave vmcnt + s_barrier TOGETHER (per-wave
//   vmcnt alone says nothing about other waves' loads).
// MODE 1: score GEMM; epilogue writes E=exp(s) bf16 (masked -> 0) + atomic
//         row-sum accumulation into denom[].
// MODE 0: out GEMM; epilogue divides by denom[row], stores f32.
// MODE 2: out GEMM fallback (in-loop rowsum from A fragments, no denom).
// ---------------------------------------------------------------------------
template <int MODE>
__global__ __launch_bounds__(512, 2) void gemm_bt(
    const u16* __restrict__ A, const u16* __restrict__ Bm,
    void* __restrict__ C, const float* __restrict__ mask,
    float* __restrict__ denom, int K, int ld, int ldc,
    size_t sA, size_t sB, size_t sC) {
  __shared__ __align__(16) u16 As[4 * 8192];   // 4 planes x 16 KiB = 64 KiB
  __shared__ __align__(16) u16 Bs[4 * 8192];

  const int tid = threadIdx.x;
  const int lane = tid & 63, w = tid >> 6;
  const int lm = lane & 15, quad = (lane >> 4) & 3;
  const int wm = (w >> 2) * 128, wn = (w & 3) * 64;

  // ---- swizzle: batch = bid&7 (XCD affinity), GM=4 m-groups, n-fast ----
  const int tiles_n = gridDim.x;
  int bid = (blockIdx.z * gridDim.y + blockIdx.y) * tiles_n + blockIdx.x;
  int bz = bid & 7;
  int s = bid >> 3;
  const int GM = 4;
  int per_group = GM * tiles_n;
  int group = s / per_group;
  int rem = s - group * per_group;
  int tm = group * GM + (rem & (GM - 1));
  int tn = rem >> 2;   // rem / GM

  const u16* Ab = A  + (size_t)bz * sA + (size_t)(tm * 256) * ld;
  const u16* Bb = Bm + (size_t)bz * sB + (size_t)(tn * 256) * ld;

  // Staging: one half-tile (256 rows x 32 k = 16 KiB = 1024 chunks of 16 B)
  // per stage call; thread covers chunks c = tid, tid+512. LDS dest linear
  // (chunk c at byte c*16, per-wave base + lane*16); global source
  // pre-swizzled:  row = c>>2, slot = (c&3) ^ ((row>>1)&3)   (involution)
  int goff[2], ldst[2];
#pragma unroll
  for (int j = 0; j < 2; j++) {
    int c = tid + 512 * j;
    int row = c >> 2;
    int slot = (c & 3) ^ ((row >> 1) & 3);
    goff[j] = row * ld + slot * 8;   // elements
    ldst[j] = c * 8;                 // elements within plane
  }

  // Fragment-read addressing: logical (row, slot=quad) -> swizzled slot.
  // row = base16 + lm so (row>>1)&3 == (lm>>1)&3 (base16 multiple of 16).
  const int sw = quad ^ ((lm >> 1) & 3);
  const int aoff = (wm + lm) * 32 + sw * 8;   // + (MH*4+m)*512 per fragment
  const int boff = (wn + lm) * 32 + sw * 8;   // + n*512 per fragment

  auto stageA = [&](int koff, int plane) {
#pragma unroll
    for (int j = 0; j < 2; j++)
      __builtin_amdgcn_global_load_lds((GAS void*)(Ab + goff[j] + koff),
                                       (LAS void*)(As + (plane << 13) + ldst[j]),
                                       16, 0, 0);
  };
  auto stageB = [&](int koff, int plane) {
#pragma unroll
    for (int j = 0; j < 2; j++)
      __builtin_amdgcn_global_load_lds((GAS void*)(Bb + goff[j] + koff),
                                       (LAS void*)(Bs + (plane << 13) + ldst[j]),
                                       16, 0, 0);
  };

  floatx4 acc[8][4];
#pragma unroll
  for (int i = 0; i < 8; i++)
#pragma unroll
    for (int j = 0; j < 4; j++)
      acc[i][j] = {0.f, 0.f, 0.f, 0.f};

  float rs[8] = {0.f, 0.f, 0.f, 0.f, 0.f, 0.f, 0.f, 0.f};   // MODE 2 only
  short8 bf[4];   // B fragments: loaded at MH==0 phases, reused at MH==1

#define WAIT4 { asm volatile("s_waitcnt vmcnt(4)" ::: "memory"); \
                __builtin_amdgcn_sched_barrier(0); }
#define WAIT0 { asm volatile("s_waitcnt vmcnt(0)" ::: "memory"); \
                __builtin_amdgcn_sched_barrier(0); }

// One phase: reads + stage (between previous closing barrier and this
// opening barrier), then barrier / lgkm-drain / MFMA cluster / optional
// counted-vmcnt / closing barrier. sched_barrier(0) pins each region
// (rule #18: inline-asm waits don't order register-only MFMA by themselves).
#define PHASE(MH, KK, CUR, STG, WPRE)                                         \
  {                                                                           \
    __builtin_amdgcn_sched_barrier(0);                                        \
    const u16* Ap = As + (((CUR) * 2 + (KK)) << 13);                          \
    if ((MH) == 0) {                                                          \
      const u16* Bp = Bs + (((CUR) * 2 + (KK)) << 13);                        \
      _Pragma("unroll")                                                       \
      for (int n = 0; n < 4; n++)                                             \
        bf[n] = *(const short8*)(Bp + boff + n * 512);                        \
    }                                                                         \
    short8 af[4];                                                             \
    _Pragma("unroll")                                                         \
    for (int m = 0; m < 4; m++)                                               \
      af[m] = *(const short8*)(Ap + aoff + ((MH) * 4 + m) * 512);             \
    STG;                                                                      \
    __builtin_amdgcn_s_barrier();                                             \
    asm volatile("s_waitcnt lgkmcnt(0)" ::: "memory");                        \
    __builtin_amdgcn_sched_barrier(0);                                        \
    if constexpr (MODE == 2) {                                                \
      _Pragma("unroll")                                                       \
      for (int m = 0; m < 4; m++) {                                           \
        uint4 u = *(const uint4*)&af[m];                                      \
        rs[(MH) * 4 + m] +=                                                   \
            __uint_as_float(u.x << 16) + __uint_as_float(u.x & 0xffff0000u)   \
          + __uint_as_float(u.y << 16) + __uint_as_float(u.y & 0xffff0000u)   \
          + __uint_as_float(u.z << 16) + __uint_as_float(u.z & 0xffff0000u)   \
          + __uint_as_float(u.w << 16) + __uint_as_float(u.w & 0xffff0000u);  \
      }                                                                       \
    }                                                                         \
    __builtin_amdgcn_s_setprio(1);                                            \
    _Pragma("unroll")                                                         \
    for (int m = 0; m < 4; m++)                                               \
      _Pragma("unroll")                                                       \
      for (int n = 0; n < 4; n++)                                             \
        acc[(MH) * 4 + m][n] = __builtin_amdgcn_mfma_f32_16x16x32_bf16(       \
            af[m], bf[n], acc[(MH) * 4 + m][n], 0, 0, 0);                     \
    __builtin_amdgcn_s_setprio(0);                                            \
    __builtin_amdgcn_sched_barrier(0);                                        \
    WPRE;                                                                     \
    __builtin_amdgcn_s_barrier();                                             \
  }

  const int NT = K >> 6;
  // prologue: stage tile 0 fully into buffer 0 (planes 0=k0, 1=k1); 8 insts
  stageA(0, 0); stageB(0, 0); stageA(32, 1); stageB(32, 1);
  WAIT4;                                   // k0 pair resident, k1 in flight
  __builtin_amdgcn_s_barrier();

  for (int t = 0; t < NT; ++t) {
    const int cur = t & 1, nb = cur ^ 1;
    const bool have = (t + 1 < NT);
    const int k0n = (t + 1) << 6;

    PHASE(0, 0, cur, if (have) stageA(k0n, nb * 2),          {})
    PHASE(1, 0, cur, if (have) stageB(k0n, nb * 2),          if (have) WAIT4 else WAIT0)
    PHASE(0, 1, cur, if (have) stageA(k0n + 32, nb * 2 + 1), {})
    PHASE(1, 1, cur, if (have) stageB(k0n + 32, nb * 2 + 1), if (have) WAIT4)
  }
#undef PHASE
#undef WAIT4
#undef WAIT0

  // C/D layout: col = lane&15, row = quad*4 + reg  [measured m89/m91]
  const int gm0 = tm * 256 + wm + quad * 4;
  const int gn0 = tn * 256 + wn + lm;
  const size_t cb = (size_t)bz * sC;

  if constexpr (MODE == 1) {
    const float* mrow = mask + (size_t)bz * LK_;
    bool msk[4];
#pragma unroll
    for (int ni = 0; ni < 4; ni++) msk[ni] = (mrow[gn0 + ni * 16] != 0.0f);
#pragma unroll
    for (int mi = 0; mi < 8; mi++) {
#pragma unroll
      for (int r = 0; r < 4; r++) {
        int row = gm0 + mi * 16 + r;
        size_t rowoff = cb + (size_t)row * ldc + gn0;
        float part = 0.f;
#pragma unroll
        for (int ni = 0; ni < 4; ni++) {
          float e = msk[ni] ? 0.f : __expf(acc[mi][ni][r]);
          u16 h = f2bf(e);
          ((u16*)C)[rowoff + ni * 16] = h;
          part += bf2f(h);   // sum the rounded value GEMM2 will actually use
        }
        if (denom) {
          part += __shfl_xor(part, 1, 64);
          part += __shfl_xor(part, 2, 64);
          part += __shfl_xor(part, 4, 64);
          part += __shfl_xor(part, 8, 64);
          if (lm == 0) atomicAdd(&denom[(size_t)bz * LQ_ + row], part);
        }
      }
    }
  } else if constexpr (MODE == 0) {
#pragma unroll
    for (int mi = 0; mi < 8; mi++) {
#pragma unroll
      for (int r = 0; r < 4; r++) {
        int row = gm0 + mi * 16 + r;
        float is = 1.0f / denom[(size_t)bz * LQ_ + row];
        size_t rowoff = cb + (size_t)row * ldc + gn0;
#pragma unroll
        for (int ni = 0; ni < 4; ni++)
          ((float*)C)[rowoff + ni * 16] = acc[mi][ni][r] * is;
      }
    }
  } else {  // MODE 2 fallback: finish in-loop rowsum
    float inv[8];
#pragma unroll
    for (int mi = 0; mi < 8; mi++) {
      rs[mi] += __shfl_xor(rs[mi], 16, 64);
      rs[mi] += __shfl_xor(rs[mi], 32, 64);
      inv[mi] = 1.0f / rs[mi];
    }
#pragma unroll
    for (int mi = 0; mi < 8; mi++) {
#pragma unroll
      for (int r = 0; r < 4; r++) {
        size_t rowoff = cb + (size_t)(gm0 + mi * 16 + r) * ldc + gn0;
        float is = __shfl(inv[mi], quad * 4 + r, 64);
#pragma unroll
        for (int ni = 0; ni < 4; ni++)
          ((float*)C)[rowoff + ni * 16] = acc[mi][ni][r] * is;
      }
    }
  }
}

// ---------------------------------------------------------------------------
// kernel_launch
// Inputs: 0=input [B,LQ,D] f32, 1=memory [B,LK,D] f32, 2=mask [B,LK] f32,
//         3=w_input [1,D] f32 (UNUSED: softmax is shift-invariant along k),
//         4=dot_scale [D] f32.
// Workspace layout (160 MB + 64 KB):
//   qb    bf16 [B,LQ,D]  @ 0        (32 MB)
//   mb    bf16 [B,LK,D]  @ 32 MB    (32 MB)
//   mbT   bf16 [B,D,LK]  @ 64 MB    (32 MB)
//   E     bf16 [B,LQ,LK] @ 96 MB    (64 MB)   (exp(scores), masked -> 0)
//   denom f32  [B,LQ]    @ 160 MB   (64 KB)   (if ws_size permits)
// ---------------------------------------------------------------------------
extern "C" void kernel_launch(void* const* d_in, const int* in_sizes, int n_in,
                              void* d_out, int out_size, void* d_ws, size_t ws_size,
                              hipStream_t stream) {
  const float* input  = (const float*)d_in[0];
  const float* memory = (const float*)d_in[1];
  const float* mask   = (const float*)d_in[2];
  const float* dscale = (const float*)d_in[4];

  char* ws = (char*)d_ws;
  u16* qb  = (u16*)(ws);
  u16* mb  = (u16*)(ws + (size_t)32 * 1024 * 1024);
  u16* mbT = (u16*)(ws + (size_t)64 * 1024 * 1024);
  u16* E   = (u16*)(ws + (size_t)96 * 1024 * 1024);
  size_t base = (size_t)160 * 1024 * 1024;
  bool have_denom = ws_size >= base + (size_t)B_ * LQ_ * sizeof(float);
  float* denom = have_denom ? (float*)(ws + base) : nullptr;
  float* out = (float*)d_out;

  hipLaunchKernelGGL(prep, dim3(32, 32, B_), dim3(256), 0, stream,
                     input, memory, dscale, qb, mb, mbT, denom);
  // E = exp(qb * mb^T), masked -> 0 : M=LQ, N=LK, K=D (+ denom accumulation)
  hipLaunchKernelGGL((gemm_bt<1>), dim3(LK_ / 256, LQ_ / 256, B_), dim3(512), 0,
                     stream, qb, mb, (void*)E, mask, denom, D_, D_, LK_,
                     (size_t)LQ_ * D_, (size_t)LK_ * D_, (size_t)LQ_ * LK_);
  // out = (E * mbT^T) / denom : M=LQ, N=D, K=LK
  if (have_denom)
    hipLaunchKernelGGL((gemm_bt<0>), dim3(D_ / 256, LQ_ / 256, B_), dim3(512), 0,
                       stream, E, mbT, (void*)out, nullptr, denom, LK_, LK_, D_,
                       (size_t)LQ_ * LK_, (size_t)D_ * LK_, (size_t)LQ_ * D_);
  else
    hipLaunchKernelGGL((gemm_bt<2>), dim3(D_ / 256, LQ_ / 256, B_), dim3(512), 0,
                       stream, E, mbT, (void*)out, nullptr, nullptr, LK_, LK_, D_,
                       (size_t)LQ_ * LK_, (size_t)D_ * LK_, (size_t)LQ_ * D_);
}

// Round 3
// 314.125 us; speedup vs baseline: 1.0338x; 1.0338x over previous
//
#include <hip/hip_runtime.h>

// Problem constants (B, LQ, LK, D from the reference)
#define B_  8
#define LQ_ 2048
#define LK_ 2048
#define D_  1024

typedef unsigned short u16;
using short8  = __attribute__((ext_vector_type(8))) short;   // 8 bf16 = 4 VGPRs (MFMA A/B frag)
using floatx4 = __attribute__((ext_vector_type(4))) float;   // MFMA C/D frag

#define GAS __attribute__((address_space(1)))
#define LAS __attribute__((address_space(3)))

__device__ __forceinline__ u16 f2bf(float f) {
  unsigned u = __float_as_uint(f);
  u += 0x7fffu + ((u >> 16) & 1u);   // round-to-nearest-even
  return (u16)(u >> 16);
}
__device__ __forceinline__ float bf2f(u16 h) {
  return __uint_as_float(((unsigned)h) << 16);
}

// ---------------------------------------------------------------------------
// prep (unchanged): blockIdx.y < 16  -> memory path: mb = bf16(memory),
//                                      mbT = bf16(memory)^T
//                   blockIdx.y >= 16 -> input path: qb = bf16(input*dot_scale)
// One designated block additionally zeroes the softmax-denominator buffer.
// ---------------------------------------------------------------------------
__global__ void prep(const float* __restrict__ in, const float* __restrict__ mem,
                     const float* __restrict__ ds, u16* __restrict__ qb,
                     u16* __restrict__ mb, u16* __restrict__ mbT,
                     float* __restrict__ denom) {
  __shared__ u16 tile[64][68];   // pad 68 to break power-of-2 bank stride
  int tid = threadIdx.x;
  int tx = tid & 15, ty = tid >> 4;
  int b = blockIdx.z;

  if (denom && blockIdx.y == 16 && blockIdx.x == 0 && blockIdx.z == 0) {
    float4 z = {0.f, 0.f, 0.f, 0.f};
    float4* d4 = (float4*)denom;
#pragma unroll
    for (int i = 0; i < (B_ * LQ_ / 4) / 256; i++)
      d4[tid + i * 256] = z;
  }

  if (blockIdx.y < 16) {
    // ---- memory path: convert + transpose ----
    int k0 = blockIdx.x * 64, d0 = blockIdx.y * 64;
    const float* mB = mem + (size_t)b * LK_ * D_;
    u16* mbB = mb  + (size_t)b * LK_ * D_;
    u16* mtB = mbT + (size_t)b * D_ * LK_;
#pragma unroll
    for (int i = 0; i < 4; i++) {
      int r = ty + 16 * i;                   // k-row within tile
      float4 v = *(const float4*)(mB + (size_t)(k0 + r) * D_ + d0 + tx * 4);
      ushort4 h;
      h.x = f2bf(v.x); h.y = f2bf(v.y); h.z = f2bf(v.z); h.w = f2bf(v.w);
      *(ushort4*)(mbB + (size_t)(k0 + r) * D_ + d0 + tx * 4) = h;
      *(ushort4*)(&tile[r][tx * 4]) = h;
    }
    __syncthreads();
#pragma unroll
    for (int i = 0; i < 4; i++) {
      int rr = ty + 16 * i;                  // d-row within tile
      ushort4 o;
      o.x = tile[tx * 4 + 0][rr];
      o.y = tile[tx * 4 + 1][rr];
      o.z = tile[tx * 4 + 2][rr];
      o.w = tile[tx * 4 + 3][rr];
      *(ushort4*)(mtB + (size_t)(d0 + rr) * LK_ + k0 + tx * 4) = o;
    }
  } else {
    // ---- input path: scale by dot_scale, convert ----
    int q0 = blockIdx.x * 64, d0 = (blockIdx.y - 16) * 64;
    const float* iB = in + (size_t)b * LQ_ * D_;
    u16* qB = qb + (size_t)b * LQ_ * D_;
    float4 s4 = *(const float4*)(ds + d0 + tx * 4);
#pragma unroll
    for (int i = 0; i < 4; i++) {
      int r = ty + 16 * i;
      float4 v = *(const float4*)(iB + (size_t)(q0 + r) * D_ + d0 + tx * 4);
      ushort4 h;
      h.x = f2bf(v.x * s4.x); h.y = f2bf(v.y * s4.y);
      h.z = f2bf(v.z * s4.z); h.w = f2bf(v.w * s4.w);
      *(ushort4*)(qB + (size_t)(q0 + r) * D_ + d0 + tx * 4) = h;
    }
  }
}

// ---------------------------------------------------------------------------
// gemm_bt: C[M,N] = A[M,K] * B[N,K]^T per batch.
// Geometry (unchanged, proven 0-bank-conflict): 256x256 tile, BK=64,
//   8 waves (2M x 4N), wave output 128x64 (acc[8][4] 16x16x32 frags).
//   LDS 128 KiB = per matrix 4 planes of 16 KiB [buf][khalf][256 rows][32 k],
//   XOR chunk swizzle slot^=((row>>1)&3) applied to BOTH the global source
//   and the ds_read address (dest linear — rule 21).
// SCHEDULE v3 (single barrier per phase, merged MH phases):
//   2 phases per K-tile (KK = k-half). Phase:
//     { ds_read af x8 + bf x4 (12 b128); stage A+B half-tile of t+1;
//       lgkmcnt(8) pre-drain; counted vmcnt; ONE s_barrier; lgkmcnt(0);
//       setprio(1); 32 MFMA; setprio(0) }
//   Per tile: 2 barriers + 2 lgkm drains (was 8 + 4) — the round-2 counters
//   showed ~4500cy/tile of sync overhead vs 2483cy dense MFMA; this halves
//   the overhead events twice.
//   SAFETY (single barrier bounds wave skew < 1 phase):
//     - Within a tile: reads hit cur-buffer planes, stages hit nb-buffer.
//     - Across tiles: stage t+1.pA writes nb_{t+1}*2 = cur_t*2 (khalf0); any
//       straggler's in-flight reads at that moment are t.pB's (cur_t*2+1,
//       khalf1) — disjoint. Stage of khalf1 is issued only after barrier
//       t+1.pA, by which time ALL waves finished MFMA t.pB, i.e. consumed
//       khalf1 reads (lgkm0 precedes MFMA). No overlap case remains.
//   vmcnt (each stage pair = 4 insts/thread):
//     prologue: stage tile0 k0+k1 (8) -> vmcnt(4): k0 resident; barrier.
//     t.pA: reads(cur,k0); stage A+B(t+1,k0)->nb*2;   WAIT4 (completes
//           t-1.pB pair, feeding t.pB reads)           [outstanding 8->4]
//     t.pB: reads(cur,k1); stage A+B(t+1,k1)->nb*2+1; WAIT4 (completes
//           t.pA pair, feeding t+1.pA reads)           [outstanding 8->4]
//     last tile: pA has no stage -> outstanding=4 -> MUST be vmcnt(0)
//           (WAIT4 would no-op); pB: no wait needed.
//   Residency = per-wave vmcnt + the following s_barrier TOGETHER.
// MODE 1: score GEMM; epilogue writes E=exp(s) bf16 (masked -> 0) + atomic
//         row-sum accumulation into denom[].
// MODE 0: out GEMM; epilogue divides by denom[row], stores f32.
// MODE 2: out GEMM fallback (in-loop rowsum from A fragments, no denom).
// ---------------------------------------------------------------------------
template <int MODE>
__global__ __launch_bounds__(512, 2) void gemm_bt(
    const u16* __restrict__ A, const u16* __restrict__ Bm,
    void* __restrict__ C, const float* __restrict__ mask,
    float* __restrict__ denom, int K, int ld, int ldc,
    size_t sA, size_t sB, size_t sC) {
  __shared__ __align__(16) u16 As[4 * 8192];   // 4 planes x 16 KiB = 64 KiB
  __shared__ __align__(16) u16 Bs[4 * 8192];

  const int tid = threadIdx.x;
  const int lane = tid & 63, w = tid >> 6;
  const int lm = lane & 15, quad = (lane >> 4) & 3;
  const int wm = (w >> 2) * 128, wn = (w & 3) * 64;

  // ---- swizzle: batch = bid&7 (XCD affinity), GM=4 m-groups, n-fast ----
  const int tiles_n = gridDim.x;
  int bid = (blockIdx.z * gridDim.y + blockIdx.y) * tiles_n + blockIdx.x;
  int bz = bid & 7;
  int s = bid >> 3;
  const int GM = 4;
  int per_group = GM * tiles_n;
  int group = s / per_group;
  int rem = s - group * per_group;
  int tm = group * GM + (rem & (GM - 1));
  int tn = rem >> 2;   // rem / GM

  const u16* Ab = A  + (size_t)bz * sA + (size_t)(tm * 256) * ld;
  const u16* Bb = Bm + (size_t)bz * sB + (size_t)(tn * 256) * ld;

  // Staging: one half-tile (256 rows x 32 k = 16 KiB = 1024 chunks of 16 B)
  // per stage call; thread covers chunks c = tid, tid+512. LDS dest linear
  // (chunk c at byte c*16); global source pre-swizzled:
  //   row = c>>2, slot = (c&3) ^ ((row>>1)&3)   (involution)
  int goff[2], ldst[2];
#pragma unroll
  for (int j = 0; j < 2; j++) {
    int c = tid + 512 * j;
    int row = c >> 2;
    int slot = (c & 3) ^ ((row >> 1) & 3);
    goff[j] = row * ld + slot * 8;   // elements
    ldst[j] = c * 8;                 // elements within plane
  }

  // Fragment-read addressing: logical (row, slot=quad) -> swizzled slot.
  // row = base16 + lm so (row>>1)&3 == (lm>>1)&3 (base16 multiple of 16).
  const int sw = quad ^ ((lm >> 1) & 3);
  const int aoff = (wm + lm) * 32 + sw * 8;   // + f*512, f=0..7 (m-frag)
  const int boff = (wn + lm) * 32 + sw * 8;   // + n*512, n=0..3 (n-frag)

  auto stageA = [&](int koff, int plane) {
#pragma unroll
    for (int j = 0; j < 2; j++)
      __builtin_amdgcn_global_load_lds((GAS void*)(Ab + goff[j] + koff),
                                       (LAS void*)(As + (plane << 13) + ldst[j]),
                                       16, 0, 0);
  };
  auto stageB = [&](int koff, int plane) {
#pragma unroll
    for (int j = 0; j < 2; j++)
      __builtin_amdgcn_global_load_lds((GAS void*)(Bb + goff[j] + koff),
                                       (LAS void*)(Bs + (plane << 13) + ldst[j]),
                                       16, 0, 0);
  };

  floatx4 acc[8][4];
#pragma unroll
  for (int i = 0; i < 8; i++)
#pragma unroll
    for (int j = 0; j < 4; j++)
      acc[i][j] = {0.f, 0.f, 0.f, 0.f};

  float rs[8] = {0.f, 0.f, 0.f, 0.f, 0.f, 0.f, 0.f, 0.f};   // MODE 2 only

#define WAIT4 { asm volatile("s_waitcnt vmcnt(4)" ::: "memory"); \
                __builtin_amdgcn_sched_barrier(0); }
#define WAIT0 { asm volatile("s_waitcnt vmcnt(0)" ::: "memory"); \
                __builtin_amdgcn_sched_barrier(0); }

// One phase: 12 ds_reads + stage pair, counted lgkm pre-drain, counted
// vmcnt, ONE barrier, lgkm drain, 32-MFMA cluster. sched_barrier(0) pins
// each region (rule #18: inline-asm waits don't order register-only MFMA).
#define PHASE(KK, CUR, STG, W)                                                \
  {                                                                           \
    __builtin_amdgcn_sched_barrier(0);                                        \
    const u16* Ap = As + (((CUR) * 2 + (KK)) << 13);                          \
    const u16* Bp = Bs + (((CUR) * 2 + (KK)) << 13);                          \
    short8 bf[4], af[8];                                                      \
    _Pragma("unroll")                                                         \
    for (int n = 0; n < 4; n++)                                               \
      bf[n] = *(const short8*)(Bp + boff + n * 512);                          \
    _Pragma("unroll")                                                         \
    for (int m = 0; m < 8; m++)                                               \
      af[m] = *(const short8*)(Ap + aoff + m * 512);                          \
    STG;                                                                      \
    asm volatile("s_waitcnt lgkmcnt(8)" ::: "memory");                        \
    __builtin_amdgcn_sched_barrier(0);                                        \
    W;                                                                        \
    __builtin_amdgcn_s_barrier();                                             \
    asm volatile("s_waitcnt lgkmcnt(0)" ::: "memory");                        \
    __builtin_amdgcn_sched_barrier(0);                                        \
    if constexpr (MODE == 2) {                                                \
      _Pragma("unroll")                                                       \
      for (int m = 0; m < 8; m++) {                                           \
        uint4 u = *(const uint4*)&af[m];                                      \
        rs[m] +=                                                              \
            __uint_as_float(u.x << 16) + __uint_as_float(u.x & 0xffff0000u)   \
          + __uint_as_float(u.y << 16) + __uint_as_float(u.y & 0xffff0000u)   \
          + __uint_as_float(u.z << 16) + __uint_as_float(u.z & 0xffff0000u)   \
          + __uint_as_float(u.w << 16) + __uint_as_float(u.w & 0xffff0000u);  \
      }                                                                       \
    }                                                                         \
    __builtin_amdgcn_s_setprio(1);                                            \
    _Pragma("unroll")                                                         \
    for (int m = 0; m < 8; m++)                                               \
      _Pragma("unroll")                                                       \
      for (int n = 0; n < 4; n++)                                             \
        acc[m][n] = __builtin_amdgcn_mfma_f32_16x16x32_bf16(                  \
            af[m], bf[n], acc[m][n], 0, 0, 0);                                \
    __builtin_amdgcn_s_setprio(0);                                            \
    __builtin_amdgcn_sched_barrier(0);                                        \
  }

  const int NT = K >> 6;
  // prologue: stage tile 0 fully into buffer 0 (planes 0=k0, 1=k1); 8 insts.
  // WAIT4 -> k0 pair resident; barrier collectivizes before first reads.
  stageA(0, 0); stageB(0, 0); stageA(32, 1); stageB(32, 1);
  WAIT4;
  __builtin_amdgcn_s_barrier();

  for (int t = 0; t < NT; ++t) {
    const int cur = t & 1, nb = cur ^ 1;
    const bool have = (t + 1 < NT);
    const int k0n = (t + 1) << 6;

    PHASE(0, cur,
          if (have) { stageA(k0n, nb * 2); stageB(k0n, nb * 2); },
          if (have) WAIT4 else WAIT0)
    PHASE(1, cur,
          if (have) { stageA(k0n + 32, nb * 2 + 1); stageB(k0n + 32, nb * 2 + 1); },
          if (have) WAIT4)
  }
#undef PHASE
#undef WAIT4
#undef WAIT0

  // C/D layout: col = lane&15, row = quad*4 + reg  [measured m89/m91]
  const int gm0 = tm * 256 + wm + quad * 4;
  const int gn0 = tn * 256 + wn + lm;
  const size_t cb = (size_t)bz * sC;

  if constexpr (MODE == 1) {
    const float* mrow = mask + (size_t)bz * LK_;
    bool msk[4];
#pragma unroll
    for (int ni = 0; ni < 4; ni++) msk[ni] = (mrow[gn0 + ni * 16] != 0.0f);
#pragma unroll
    for (int mi = 0; mi < 8; mi++) {
#pragma unroll
      for (int r = 0; r < 4; r++) {
        int row = gm0 + mi * 16 + r;
        size_t rowoff = cb + (size_t)row * ldc + gn0;
        float part = 0.f;
#pragma unroll
        for (int ni = 0; ni < 4; ni++) {
          float e = msk[ni] ? 0.f : __expf(acc[mi][ni][r]);
          u16 h = f2bf(e);
          ((u16*)C)[rowoff + ni * 16] = h;
          part += bf2f(h);   // sum the rounded value GEMM2 will actually use
        }
        if (denom) {
          part += __shfl_xor(part, 1, 64);
          part += __shfl_xor(part, 2, 64);
          part += __shfl_xor(part, 4, 64);
          part += __shfl_xor(part, 8, 64);
          if (lm == 0) atomicAdd(&denom[(size_t)bz * LQ_ + row], part);
        }
      }
    }
  } else if constexpr (MODE == 0) {
#pragma unroll
    for (int mi = 0; mi < 8; mi++) {
#pragma unroll
      for (int r = 0; r < 4; r++) {
        int row = gm0 + mi * 16 + r;
        float is = 1.0f / denom[(size_t)bz * LQ_ + row];
        size_t rowoff = cb + (size_t)row * ldc + gn0;
#pragma unroll
        for (int ni = 0; ni < 4; ni++)
          ((float*)C)[rowoff + ni * 16] = acc[mi][ni][r] * is;
      }
    }
  } else {  // MODE 2 fallback: finish in-loop rowsum
    float inv[8];
#pragma unroll
    for (int mi = 0; mi < 8; mi++) {
      rs[mi] += __shfl_xor(rs[mi], 16, 64);
      rs[mi] += __shfl_xor(rs[mi], 32, 64);
      inv[mi] = 1.0f / rs[mi];
    }
#pragma unroll
    for (int mi = 0; mi < 8; mi++) {
#pragma unroll
      for (int r = 0; r < 4; r++) {
        size_t rowoff = cb + (size_t)(gm0 + mi * 16 + r) * ldc + gn0;
        float is = __shfl(inv[mi], quad * 4 + r, 64);
#pragma unroll
        for (int ni = 0; ni < 4; ni++)
          ((float*)C)[rowoff + ni * 16] = acc[mi][ni][r] * is;
      }
    }
  }
}

// ---------------------------------------------------------------------------
// kernel_launch
// Inputs: 0=input [B,LQ,D] f32, 1=memory [B,LK,D] f32, 2=mask [B,LK] f32,
//         3=w_input [1,D] f32 (UNUSED: softmax is shift-invariant along k),
//         4=dot_scale [D] f32.
// Workspace layout (160 MB + 64 KB):
//   qb    bf16 [B,LQ,D]  @ 0        (32 MB)
//   mb    bf16 [B,LK,D]  @ 32 MB    (32 MB)
//   mbT   bf16 [B,D,LK]  @ 64 MB    (32 MB)
//   E     bf16 [B,LQ,LK] @ 96 MB    (64 MB)   (exp(scores), masked -> 0)
//   denom f32  [B,LQ]    @ 160 MB   (64 KB)   (if ws_size permits)
// ---------------------------------------------------------------------------
extern "C" void kernel_launch(void* const* d_in, const int* in_sizes, int n_in,
                              void* d_out, int out_size, void* d_ws, size_t ws_size,
                              hipStream_t stream) {
  const float* input  = (const float*)d_in[0];
  const float* memory = (const float*)d_in[1];
  const float* mask   = (const float*)d_in[2];
  const float* dscale = (const float*)d_in[4];

  char* ws = (char*)d_ws;
  u16* qb  = (u16*)(ws);
  u16* mb  = (u16*)(ws + (size_t)32 * 1024 * 1024);
  u16* mbT = (u16*)(ws + (size_t)64 * 1024 * 1024);
  u16* E   = (u16*)(ws + (size_t)96 * 1024 * 1024);
  size_t base = (size_t)160 * 1024 * 1024;
  bool have_denom = ws_size >= base + (size_t)B_ * LQ_ * sizeof(float);
  float* denom = have_denom ? (float*)(ws + base) : nullptr;
  float* out = (float*)d_out;

  hipLaunchKernelGGL(prep, dim3(32, 32, B_), dim3(256), 0, stream,
                     input, memory, dscale, qb, mb, mbT, denom);
  // E = exp(qb * mb^T), masked -> 0 : M=LQ, N=LK, K=D (+ denom accumulation)
  hipLaunchKernelGGL((gemm_bt<1>), dim3(LK_ / 256, LQ_ / 256, B_), dim3(512), 0,
                     stream, qb, mb, (void*)E, mask, denom, D_, D_, LK_,
                     (size_t)LQ_ * D_, (size_t)LK_ * D_, (size_t)LQ_ * LK_);
  // out = (E * mbT^T) / denom : M=LQ, N=D, K=LK
  if (have_denom)
    hipLaunchKernelGGL((gemm_bt<0>), dim3(D_ / 256, LQ_ / 256, B_), dim3(512), 0,
                       stream, E, mbT, (void*)out, nullptr, denom, LK_, LK_, D_,
                       (size_t)LQ_ * LK_, (size_t)D_ * LK_, (size_t)LQ_ * D_);
  else
    hipLaunchKernelGGL((gemm_bt<2>), dim3(D_ / 256, LQ_ / 256, B_), dim3(512), 0,
                       stream, E, mbT, (void*)out, nullptr, nullptr, LK_, LK_, D_,
                       (size_t)LQ_ * LK_, (size_t)D_ * LK_, (size_t)LQ_ * D_);
}